// Round 2
// baseline (1301.698 us; speedup 1.0000x reference)
//
#include <hip/hip_runtime.h>

// ---------------------------------------------------------------------------
// MPN (chemprop) on MI355X. bf16 MFMA (16x16x32), fp32 accum.
//   relu(inp + m@W_h) == relu([f_bonds | m] @ [W_i ; W_h])  -> no stored inp.
// R1: 1-D grid, XCD-paired decode (n-half pairs 8 dispatch slots apart).
// R2: de-fused combine — msgC[b] = bf16(amsg[b2a[b]] - msg[b2revb[b]]) is
//     materialized by a streaming gather kernel (latency-tolerant, massive
//     TLP); the GEMM A-staging is now fully coalesced. GEMM writes in-place
//     over the old message (it no longer reads it), so workspace is unchanged:
//     msgA = message (persistent), msgB = combine scratch / concat,
//     hid = fbp+amsg region (dead by then).
// GEMM: LDS double-buffered, block tile 128M x 160N, wave tile 64x80 (4x5).
// Workspace (~385 MiB): wih | wto | fbp | amsg | msgA | msgB
// ---------------------------------------------------------------------------

#define DEVFN static __device__ __forceinline__

typedef __attribute__((ext_vector_type(8))) __bf16 bf16x8;
typedef __attribute__((ext_vector_type(4))) float floatx4;

DEVFN unsigned short f2bf(float f) {
    unsigned int u = __float_as_uint(f);
    u += 0x7FFFu + ((u >> 16) & 1u);   // RNE
    return (unsigned short)(u >> 16);
}
DEVFN float bf2f(unsigned int u) { return __uint_as_float(u << 16); }

// packed bf16x2 subtract via fp32 (exact in fp32, RNE back)
DEVFN unsigned int bfsub2(unsigned int a, unsigned int m) {
    float lo = bf2f(a & 0xffffu) - bf2f(m & 0xffffu);
    float hi = bf2f(a >> 16) - bf2f(m >> 16);
    return (unsigned int)f2bf(lo) | ((unsigned int)f2bf(hi) << 16);
}
DEVFN uint4 bfsub8(uint4 a, uint4 m) {
    return make_uint4(bfsub2(a.x, m.x), bfsub2(a.y, m.y),
                      bfsub2(a.z, m.z), bfsub2(a.w, m.w));
}

// ---------------------------------------------------------------------------
__global__ __launch_bounds__(256) void dbg_fill(float* out, int n, float v) {
    int t = blockIdx.x * 256 + threadIdx.x;
    if (t < n) out[t] = v;
}

// Wih[320][480]: k<147 -> W_i[k][n]; 160<=k<460 -> W_h[k-160][n]; else 0
__global__ __launch_bounds__(256) void prep_wih(const float* __restrict__ Wi,
                                                const float* __restrict__ Wh,
                                                unsigned short* __restrict__ Wt) {
    int t = blockIdx.x * 256 + threadIdx.x;
    if (t >= 320 * 480) return;
    int n = t / 480, k = t - n * 480;
    float v = 0.f;
    if (n < 300) {
        if (k < 147) v = Wi[k * 300 + n];
        else if (k >= 160 && k < 460) v = Wh[(k - 160) * 300 + n];
    }
    Wt[t] = f2bf(v);
}

// Wto[320][448]: k<300 -> W_o[133+k][n]; 304<=k<437 -> W_o[k-304][n]; else 0
__global__ __launch_bounds__(256) void prep_wto(const float* __restrict__ Wo,
                                                unsigned short* __restrict__ Wt) {
    int t = blockIdx.x * 256 + threadIdx.x;
    if (t >= 320 * 448) return;
    int n = t / 448, k = t - n * 448;
    float v = 0.f;
    if (n < 300) {
        if (k < 300) v = Wo[(133 + k) * 300 + n];
        else if (k >= 304 && k < 437) v = Wo[(k - 304) * 300 + n];
    }
    Wt[t] = f2bf(v);
}

// f_bonds [200000][147] fp32 -> [200000][160] bf16 padded
__global__ __launch_bounds__(256) void pad_bonds(const float* __restrict__ fb,
                                                 unsigned short* __restrict__ out) {
    int t = blockIdx.x * 256 + threadIdx.x;
    if (t >= 200000 * 20) return;
    int b = t / 20, c = t - b * 20;
    unsigned int o[4];
#pragma unroll
    for (int p = 0; p < 4; ++p) {
        int sc = c * 8 + p * 2;
        float v0 = (sc < 147) ? fb[(size_t)b * 147 + sc] : 0.f;
        float v1 = (sc + 1 < 147) ? fb[(size_t)b * 147 + sc + 1] : 0.f;
        o[p] = (unsigned int)f2bf(v0) | ((unsigned int)f2bf(v1) << 16);
    }
    *(uint4*)(out + (size_t)b * 160 + c * 8) = make_uint4(o[0], o[1], o[2], o[3]);
}

// f_atoms [100000][133] fp32 -> concat cols 304..447
__global__ __launch_bounds__(256) void atoms_concat(const float* __restrict__ fa,
                                                    unsigned short* __restrict__ concat) {
    int t = blockIdx.x * 256 + threadIdx.x;
    if (t >= 100000 * 18) return;
    int a = t / 18, c = t - a * 18;
    unsigned int o[4];
#pragma unroll
    for (int p = 0; p < 4; ++p) {
        int sc = c * 8 + p * 2;
        float v0 = (sc < 133) ? fa[(size_t)a * 133 + sc] : 0.f;
        float v1 = (sc + 1 < 133) ? fa[(size_t)a * 133 + sc + 1] : 0.f;
        o[p] = (unsigned int)f2bf(v0) | ((unsigned int)f2bf(v1) << 16);
    }
    *(uint4*)(concat + (size_t)a * 448 + 304 + c * 8) = make_uint4(o[0], o[1], o[2], o[3]);
}

// a_msg[a] = sum_j msg[a2b[a][j]]
template <int CH>
__global__ __launch_bounds__(256) void gather_sum(const unsigned short* __restrict__ msg,
                                                  const int* __restrict__ a2b,
                                                  unsigned short* __restrict__ out,
                                                  int ostride, int nA) {
    int t = blockIdx.x * 256 + threadIdx.x;
    if (t >= nA * CH) return;
    int a = t / CH, c = t - a * CH;
    float s[8] = {0, 0, 0, 0, 0, 0, 0, 0};
#pragma unroll
    for (int j = 0; j < 6; ++j) {
        int b = a2b[a * 6 + j];
        uint4 v = *(const uint4*)(msg + (size_t)b * 320 + c * 8);
        s[0] += bf2f(v.x & 0xffffu); s[1] += bf2f(v.x >> 16);
        s[2] += bf2f(v.y & 0xffffu); s[3] += bf2f(v.y >> 16);
        s[4] += bf2f(v.z & 0xffffu); s[5] += bf2f(v.z >> 16);
        s[6] += bf2f(v.w & 0xffffu); s[7] += bf2f(v.w >> 16);
    }
    unsigned int o[4];
#pragma unroll
    for (int p = 0; p < 4; ++p)
        o[p] = (unsigned int)f2bf(s[2 * p]) | ((unsigned int)f2bf(s[2 * p + 1]) << 16);
    *(uint4*)(out + (size_t)a * ostride + c * 8) = make_uint4(o[0], o[1], o[2], o[3]);
}

// msgC[b] = bf16(amsg[b2a[b]] - msg[b2revb[b]])  — streaming gather, no barriers
__global__ __launch_bounds__(256) void combine_k(const unsigned short* __restrict__ amsg,
                                                 const unsigned short* __restrict__ msg,
                                                 const int* __restrict__ b2a,
                                                 const int* __restrict__ b2revb,
                                                 unsigned short* __restrict__ msgC) {
    int t = blockIdx.x * 256 + threadIdx.x;
    if (t >= 200000 * 40) return;
    int b = t / 40, c = t - b * 40;
    uint4 va = *(const uint4*)(amsg + (size_t)b2a[b] * 320 + c * 8);
    uint4 vm = *(const uint4*)(msg + (size_t)b2revb[b] * 320 + c * 8);
    *(uint4*)(msgC + (size_t)b * 320 + c * 8) = bfsub8(va, vm);
}

// ---------------------------------------------------------------------------
// LDS-staged GEMM.  C[M][320] = [A0 | A1] @ Wt^T     (all A reads coalesced)
//   Wt[320][BSTRIDE] k-contiguous rows (weight columns).
//   Block: 128M x 160N; 4 waves 2x2; wave 64x80.
//   Grid: 1-D, 2*MB blocks, XCD-paired decode (see R1 note above).
//   K = (KT0+KT1)*32. kt<KT0: A from A0 (stride a0s). kt>=KT0: A from A1
//   (stride 320, row-linear — the combine is pre-materialized).
// MODE 0: outp[r*320+col] = relu(acc) bf16
// MODE 2: hid[r*300+col]  = relu(acc + bo[col]) fp32  (col<300)
// LDS: As 2x[128][40] bf16 (pad->2-way, free), Bs 2x[160][32] bf16 with XOR
//      k-quarter swizzle (unit q stored at q^(n&3)) -> 2-way, free.
// ---------------------------------------------------------------------------
template <int KT0, int KT1, int MODE, int BSTRIDE>
__global__ __launch_bounds__(256) void gemm_k(const unsigned short* __restrict__ A0,
                                              int a0s,
                                              const unsigned short* __restrict__ A1,
                                              const unsigned short* __restrict__ Wt,
                                              unsigned short* __restrict__ outp,
                                              float* __restrict__ hid,
                                              const float* __restrict__ bo, int M) {
    constexpr int KT = KT0 + KT1;
    __shared__ unsigned short As[2 * 5120];   // [buf][128][40]
    __shared__ unsigned short Bs[2 * 5120];   // [buf][160][32] swizzled

    const int tid = threadIdx.x;
    const int lane = tid & 63;
    const int wave = tid >> 6;
    const int wm = wave & 1, wn = wave >> 1;
    const int l16 = lane & 15, quad = lane >> 4;

    // ---- XCD-paired m/n decode (bijective incl. tail) ----
    int m0, n0;
    {
        const int bid = blockIdx.x;
        const int MB = (int)(gridDim.x >> 1);
        const int mfull = (MB >> 3) << 3;        // largest mult of 8 <= MB
        const int FULL = mfull << 1;
        int mb, nh;
        if (bid < FULL) {
            nh = (bid >> 3) & 1;
            mb = ((bid >> 4) << 3) + (bid & 7);
        } else {
            const int r = bid - FULL;
            const int rem = MB - mfull;
            nh = (r >= rem) ? 1 : 0;
            mb = mfull + r - nh * rem;
        }
        m0 = mb * 128;
        n0 = nh * 160;
    }

    // ---- staging setup: A (2 threads/row), B (2.5 16B-units/thread) ----
    const int arow = tid >> 1, ahalf = tid & 1;
    const int gr = min(m0 + arow, M - 1);
    const unsigned short* a0p = A0 + (size_t)gr * a0s + ahalf * 16;
    const unsigned short* a1p = (KT1 > 0) ? (A1 + (size_t)gr * 320 + ahalf * 16) : nullptr;
    const int u0 = tid, u1 = tid + 256, u2 = tid + 512;
    const unsigned short* bg0 = Wt + (size_t)(n0 + (u0 >> 2)) * BSTRIDE + ((u0 ^ (u0 >> 2)) & 3) * 8;
    const unsigned short* bg1 = Wt + (size_t)(n0 + (u1 >> 2)) * BSTRIDE + ((u1 ^ (u1 >> 2)) & 3) * 8;
    const unsigned short* bg2 = (tid < 128)
        ? Wt + (size_t)(n0 + (u2 >> 2)) * BSTRIDE + ((u2 ^ (u2 >> 2)) & 3) * 8 : Wt;

    // ---- fragment LDS offsets (shorts) ----
    int aoff[4], boff[5];
#pragma unroll
    for (int tm = 0; tm < 4; ++tm)
        aoff[tm] = (wm * 64 + tm * 16 + l16) * 40 + quad * 8;
#pragma unroll
    for (int tn = 0; tn < 5; ++tn) {
        int nl = wn * 80 + tn * 16 + l16;
        boff[tn] = nl * 32 + ((quad ^ nl) & 3) * 8;
    }

    floatx4 acc[4][5];
#pragma unroll
    for (int tm = 0; tm < 4; ++tm)
#pragma unroll
        for (int tn = 0; tn < 5; ++tn) acc[tm][tn] = (floatx4){0.f, 0.f, 0.f, 0.f};

    uint4 ar0, ar1, br0, br1, br2;
    auto ldG = [&](int kt) {
        if (kt < KT0) {
            ar0 = *(const uint4*)(a0p + kt * 32);
            ar1 = *(const uint4*)(a0p + kt * 32 + 8);
        } else {
            int ko = (kt - KT0) * 32;
            ar0 = *(const uint4*)(a1p + ko);
            ar1 = *(const uint4*)(a1p + ko + 8);
        }
        br0 = *(const uint4*)(bg0 + kt * 32);
        br1 = *(const uint4*)(bg1 + kt * 32);
        if (tid < 128) br2 = *(const uint4*)(bg2 + kt * 32);
    };
    auto stW = [&](int buf) {
        unsigned short* ab = As + buf * 5120 + arow * 40 + ahalf * 16;
        *(uint4*)(ab) = ar0;
        *(uint4*)(ab + 8) = ar1;
        unsigned short* bb = Bs + buf * 5120;
        *(uint4*)(bb + u0 * 8) = br0;
        *(uint4*)(bb + u1 * 8) = br1;
        if (tid < 128) *(uint4*)(bb + u2 * 8) = br2;
    };

    ldG(0);
    stW(0);
    __syncthreads();

#pragma unroll
    for (int kt = 0; kt < KT; ++kt) {
        const int buf = kt & 1;
        if (kt + 1 < KT) ldG(kt + 1);

        bf16x8 av[4], bv[5];
#pragma unroll
        for (int tm = 0; tm < 4; ++tm)
            av[tm] = *(const bf16x8*)(As + buf * 5120 + aoff[tm]);
#pragma unroll
        for (int tn = 0; tn < 5; ++tn)
            bv[tn] = *(const bf16x8*)(Bs + buf * 5120 + boff[tn]);
#pragma unroll
        for (int tn = 0; tn < 5; ++tn)
#pragma unroll
            for (int tm = 0; tm < 4; ++tm)
                acc[tm][tn] = __builtin_amdgcn_mfma_f32_16x16x32_bf16(av[tm], bv[tn], acc[tm][tn], 0, 0, 0);

        if (kt + 1 < KT) stW(buf ^ 1);
        __syncthreads();
    }

    // ---- epilogue ----
    float bias[5];
    if (MODE == 2) {
#pragma unroll
        for (int tn = 0; tn < 5; ++tn) {
            int col = n0 + wn * 80 + tn * 16 + l16;
            bias[tn] = (col < 300) ? bo[col] : 0.f;
        }
    }
#pragma unroll
    for (int tm = 0; tm < 4; ++tm) {
        const int r0 = m0 + wm * 64 + tm * 16 + quad * 4;
#pragma unroll
        for (int tn = 0; tn < 5; ++tn) {
            const int col = n0 + wn * 80 + tn * 16 + l16;
#pragma unroll
            for (int i = 0; i < 4; ++i) {
                int r = r0 + i;
                if (r >= M) continue;
                float c = acc[tm][tn][i];
                if (MODE == 2) {
                    if (col < 300) hid[(size_t)r * 300 + col] = fmaxf(c + bias[tn], 0.f);
                } else {
                    outp[(size_t)r * 320 + col] = f2bf(fmaxf(c, 0.f));
                }
            }
        }
    }
}

// ---------------------------------------------------------------------------
// Per-molecule mean. mol_ids sorted -> binary search row range.
// ---------------------------------------------------------------------------
__global__ __launch_bounds__(320) void mean_k(const float* __restrict__ hid,
                                              const int* __restrict__ mol_ids,
                                              float* __restrict__ out, int nA) {
    int mol = blockIdx.x;
    int lo, hi;
    {
        int l = 0, h = nA;
        while (l < h) { int m = (l + h) >> 1; if (mol_ids[m] < mol) l = m + 1; else h = m; }
        lo = l;
    }
    {
        int l = lo, h = nA;
        while (l < h) { int m = (l + h) >> 1; if (mol_ids[m] < mol + 1) l = m + 1; else h = m; }
        hi = l;
    }
    int col = threadIdx.x;
    if (col >= 300) return;
    float s = 0.f;
    for (int a = lo; a < hi; ++a) s += hid[(size_t)a * 300 + col];
    int cnt = hi - lo;
    out[(size_t)mol * 300 + col] = s / (float)(cnt > 0 ? cnt : 1);
}

// ---------------------------------------------------------------------------
extern "C" void kernel_launch(void* const* d_in, const int* in_sizes, int n_in,
                              void* d_out, int out_size, void* d_ws, size_t ws_size,
                              hipStream_t stream) {
    (void)in_sizes; (void)n_in;
    const float* f_atoms = (const float*)d_in[0];
    const float* f_bonds = (const float*)d_in[1];
    const float* W_i     = (const float*)d_in[2];
    const float* W_h     = (const float*)d_in[3];
    const float* W_o     = (const float*)d_in[4];
    const float* b_o     = (const float*)d_in[5];
    const int*   a2b     = (const int*)d_in[6];
    const int*   b2a     = (const int*)d_in[7];
    const int*   b2revb  = (const int*)d_in[8];
    const int*   mol_ids = (const int*)d_in[9];

    const size_t sz_wih  = 320ull * 480 * 2;
    const size_t sz_wto  = 320ull * 448 * 2;
    const size_t sz_fbp  = 200000ull * 160 * 2;
    const size_t sz_amsg = 100000ull * 320 * 2;
    const size_t sz_msg  = 200000ull * 320 * 2;
    const size_t need = sz_wih + sz_wto + sz_fbp + sz_amsg + 2 * sz_msg;

    if (ws_size < need) {
        dbg_fill<<<(out_size + 255) / 256, 256, 0, stream>>>(
            (float*)d_out, out_size, (float)(ws_size >> 20));
        return;
    }

    char* ws = (char*)d_ws;
    unsigned short* wih  = (unsigned short*)(ws);
    unsigned short* wto  = (unsigned short*)(ws + sz_wih);
    unsigned short* fbp  = (unsigned short*)(ws + sz_wih + sz_wto);
    unsigned short* amsg = (unsigned short*)(ws + sz_wih + sz_wto + sz_fbp);
    unsigned short* msgA = (unsigned short*)(ws + sz_wih + sz_wto + sz_fbp + sz_amsg);
    unsigned short* msgB = (unsigned short*)(ws + sz_wih + sz_wto + sz_fbp + sz_amsg + sz_msg);
    // msgA = persistent message; msgB = combine scratch, then concat.
    // hid overlays fbp+amsg (both dead after final gather): 120 MB <= 128 MB.
    unsigned short* concat = msgB;
    float*          hid    = (float*)fbp;

    prep_wih<<<600, 256, 0, stream>>>(W_i, W_h, wih);
    prep_wto<<<560, 256, 0, stream>>>(W_o, wto);
    pad_bonds<<<15625, 256, 0, stream>>>(f_bonds, fbp);

    // msgA = relu(f_bonds @ W_i)   (grid = 2*MB, XCD-paired decode inside)
    gemm_k<5, 0, 0, 480><<<dim3(3126), 256, 0, stream>>>(
        fbp, 160, nullptr, wih, msgA, nullptr, nullptr, 200000);

    for (int d = 0; d < 3; ++d) {   // DEPTH-1
        gather_sum<40><<<15625, 256, 0, stream>>>(msgA, a2b, amsg, 320, 100000);
        combine_k<<<31250, 256, 0, stream>>>(amsg, msgA, b2a, b2revb, msgB);
        // msgA <- relu([fbp | msgB] @ Wih) — in-place: gemm does not read msgA
        gemm_k<5, 10, 0, 480><<<dim3(3126), 256, 0, stream>>>(
            fbp, 160, msgB, wih, msgA, nullptr, nullptr, 200000);
    }

    // final gather into concat cols 0..303 (concat == msgB)
    gather_sum<38><<<14844, 256, 0, stream>>>(msgA, a2b, concat, 448, 100000);
    atoms_concat<<<7032, 256, 0, stream>>>(f_atoms, concat);
    // hid = relu(concat @ W_o + b_o)
    gemm_k<14, 0, 2, 448><<<dim3(1564), 256, 0, stream>>>(
        concat, 448, nullptr, wto, nullptr, hid, b_o, 100000);
    mean_k<<<8192, 320, 0, stream>>>(hid, mol_ids, (float*)d_out, 100000);
}

// Round 3
// 1127.812 us; speedup vs baseline: 1.1542x; 1.1542x over previous
//
#include <hip/hip_runtime.h>

// ---------------------------------------------------------------------------
// MPN (chemprop) on MI355X. bf16 MFMA (16x16x32), fp32 accum.
//   relu(inp + m@W_h) == relu([f_bonds | m] @ [W_i ; W_h])  -> no stored inp.
//   combine (a_msg[b2a[b]] - msg[b2revb[b]]) fused into GEMM A-staging.
// R1: 1-D grid, XCD-paired decode (n-half pairs 8 dispatch slots apart).
// R2: de-fused combine — REVERTED in R3 (net regression: combine_k cost 65µs
//     vs 17µs saved in GEMM; GEMM is latency-bound, not staging-bound).
// R3: depth-2 register prefetch + raw counted barrier. Loads for kt+2 issue
//     at kt, hit LDS at kt+1. __syncthreads (vmcnt(0) drain) replaced by
//     lgkmcnt(0)+s_barrier, so the compiler emits COUNTED vmcnt before the
//     LDS stores — in-flight loads ride across barriers (guide T3/T4).
// GEMM: LDS double-buffered, block tile 128M x 160N, wave tile 64x80 (4x5).
// Workspace (~367 MiB): wih | wto | fbp | amsg | msgA | msgB
// ---------------------------------------------------------------------------

#define DEVFN static __device__ __forceinline__

typedef __attribute__((ext_vector_type(8))) __bf16 bf16x8;
typedef __attribute__((ext_vector_type(4))) float floatx4;

DEVFN unsigned short f2bf(float f) {
    unsigned int u = __float_as_uint(f);
    u += 0x7FFFu + ((u >> 16) & 1u);   // RNE
    return (unsigned short)(u >> 16);
}
DEVFN float bf2f(unsigned int u) { return __uint_as_float(u << 16); }

// packed bf16x2 subtract via fp32 (exact in fp32, RNE back)
DEVFN unsigned int bfsub2(unsigned int a, unsigned int m) {
    float lo = bf2f(a & 0xffffu) - bf2f(m & 0xffffu);
    float hi = bf2f(a >> 16) - bf2f(m >> 16);
    return (unsigned int)f2bf(lo) | ((unsigned int)f2bf(hi) << 16);
}
DEVFN uint4 bfsub8(uint4 a, uint4 m) {
    return make_uint4(bfsub2(a.x, m.x), bfsub2(a.y, m.y),
                      bfsub2(a.z, m.z), bfsub2(a.w, m.w));
}

// ---------------------------------------------------------------------------
__global__ __launch_bounds__(256) void dbg_fill(float* out, int n, float v) {
    int t = blockIdx.x * 256 + threadIdx.x;
    if (t < n) out[t] = v;
}

// Wih[320][480]: k<147 -> W_i[k][n]; 160<=k<460 -> W_h[k-160][n]; else 0
__global__ __launch_bounds__(256) void prep_wih(const float* __restrict__ Wi,
                                                const float* __restrict__ Wh,
                                                unsigned short* __restrict__ Wt) {
    int t = blockIdx.x * 256 + threadIdx.x;
    if (t >= 320 * 480) return;
    int n = t / 480, k = t - n * 480;
    float v = 0.f;
    if (n < 300) {
        if (k < 147) v = Wi[k * 300 + n];
        else if (k >= 160 && k < 460) v = Wh[(k - 160) * 300 + n];
    }
    Wt[t] = f2bf(v);
}

// Wto[320][448]: k<300 -> W_o[133+k][n]; 304<=k<437 -> W_o[k-304][n]; else 0
__global__ __launch_bounds__(256) void prep_wto(const float* __restrict__ Wo,
                                                unsigned short* __restrict__ Wt) {
    int t = blockIdx.x * 256 + threadIdx.x;
    if (t >= 320 * 448) return;
    int n = t / 448, k = t - n * 448;
    float v = 0.f;
    if (n < 300) {
        if (k < 300) v = Wo[(133 + k) * 300 + n];
        else if (k >= 304 && k < 437) v = Wo[(k - 304) * 300 + n];
    }
    Wt[t] = f2bf(v);
}

// f_bonds [200000][147] fp32 -> [200000][160] bf16 padded
__global__ __launch_bounds__(256) void pad_bonds(const float* __restrict__ fb,
                                                 unsigned short* __restrict__ out) {
    int t = blockIdx.x * 256 + threadIdx.x;
    if (t >= 200000 * 20) return;
    int b = t / 20, c = t - b * 20;
    unsigned int o[4];
#pragma unroll
    for (int p = 0; p < 4; ++p) {
        int sc = c * 8 + p * 2;
        float v0 = (sc < 147) ? fb[(size_t)b * 147 + sc] : 0.f;
        float v1 = (sc + 1 < 147) ? fb[(size_t)b * 147 + sc + 1] : 0.f;
        o[p] = (unsigned int)f2bf(v0) | ((unsigned int)f2bf(v1) << 16);
    }
    *(uint4*)(out + (size_t)b * 160 + c * 8) = make_uint4(o[0], o[1], o[2], o[3]);
}

// f_atoms [100000][133] fp32 -> concat cols 304..447
__global__ __launch_bounds__(256) void atoms_concat(const float* __restrict__ fa,
                                                    unsigned short* __restrict__ concat) {
    int t = blockIdx.x * 256 + threadIdx.x;
    if (t >= 100000 * 18) return;
    int a = t / 18, c = t - a * 18;
    unsigned int o[4];
#pragma unroll
    for (int p = 0; p < 4; ++p) {
        int sc = c * 8 + p * 2;
        float v0 = (sc < 133) ? fa[(size_t)a * 133 + sc] : 0.f;
        float v1 = (sc + 1 < 133) ? fa[(size_t)a * 133 + sc + 1] : 0.f;
        o[p] = (unsigned int)f2bf(v0) | ((unsigned int)f2bf(v1) << 16);
    }
    *(uint4*)(concat + (size_t)a * 448 + 304 + c * 8) = make_uint4(o[0], o[1], o[2], o[3]);
}

// a_msg[a] = sum_j msg[a2b[a][j]]
template <int CH>
__global__ __launch_bounds__(256) void gather_sum(const unsigned short* __restrict__ msg,
                                                  const int* __restrict__ a2b,
                                                  unsigned short* __restrict__ out,
                                                  int ostride, int nA) {
    int t = blockIdx.x * 256 + threadIdx.x;
    if (t >= nA * CH) return;
    int a = t / CH, c = t - a * CH;
    float s[8] = {0, 0, 0, 0, 0, 0, 0, 0};
#pragma unroll
    for (int j = 0; j < 6; ++j) {
        int b = a2b[a * 6 + j];
        uint4 v = *(const uint4*)(msg + (size_t)b * 320 + c * 8);
        s[0] += bf2f(v.x & 0xffffu); s[1] += bf2f(v.x >> 16);
        s[2] += bf2f(v.y & 0xffffu); s[3] += bf2f(v.y >> 16);
        s[4] += bf2f(v.z & 0xffffu); s[5] += bf2f(v.z >> 16);
        s[6] += bf2f(v.w & 0xffffu); s[7] += bf2f(v.w >> 16);
    }
    unsigned int o[4];
#pragma unroll
    for (int p = 0; p < 4; ++p)
        o[p] = (unsigned int)f2bf(s[2 * p]) | ((unsigned int)f2bf(s[2 * p + 1]) << 16);
    *(uint4*)(out + (size_t)a * ostride + c * 8) = make_uint4(o[0], o[1], o[2], o[3]);
}

// ---------------------------------------------------------------------------
// LDS-staged GEMM.  C[M][320] = [A0 | combine] @ Wt^T
//   Wt[320][BSTRIDE] k-contiguous rows (weight columns).
//   Block: 128M x 160N; 4 waves 2x2; wave 64x80.
//   Grid: 1-D, 2*MB blocks, XCD-paired decode.
//   K = (KT0+KT1)*32. kt<KT0: A from A0 (stride a0s). kt>=KT0 (hidden only):
//   A row r = bf16(amsg[b2a[r]] - msg[b2revb[r]]).
// Pipeline (R3): depth-2 reg prefetch. Set P holds even kt, set Q odd kt.
//   iter kt: ldg(kt+2) -> freed set; compute LDS[kt&1]; stw(other set ->
//   LDS[(kt+1)&1]); lgkmcnt(0)+s_barrier (NO vmcnt drain: compiler emits
//   counted vmcnt before the stw stores, in-flight kt+2 loads ride across).
// MODE 0: outp[r*320+col] = relu(acc) bf16
// MODE 2: hid[r*300+col]  = relu(acc + bo[col]) fp32  (col<300)
// LDS: As 2x[128][40] bf16, Bs 2x[160][32] bf16 with XOR k-quarter swizzle.
// ---------------------------------------------------------------------------
template <int KT0, int KT1, int MODE, int BSTRIDE>
__global__ __launch_bounds__(256) void gemm_k(const unsigned short* __restrict__ A0,
                                              int a0s,
                                              const unsigned short* __restrict__ amsg,
                                              const unsigned short* __restrict__ msg,
                                              const int* __restrict__ b2a,
                                              const int* __restrict__ b2revb,
                                              const unsigned short* __restrict__ Wt,
                                              unsigned short* __restrict__ outp,
                                              float* __restrict__ hid,
                                              const float* __restrict__ bo, int M) {
    constexpr int KT = KT0 + KT1;
    __shared__ unsigned short As[2 * 5120];   // [buf][128][40]
    __shared__ unsigned short Bs[2 * 5120];   // [buf][160][32] swizzled

    const int tid = threadIdx.x;
    const int lane = tid & 63;
    const int wave = tid >> 6;
    const int wm = wave & 1, wn = wave >> 1;
    const int l16 = lane & 15, quad = lane >> 4;

    // ---- XCD-paired m/n decode (bijective incl. tail) ----
    int m0, n0;
    {
        const int bid = blockIdx.x;
        const int MB = (int)(gridDim.x >> 1);
        const int mfull = (MB >> 3) << 3;        // largest mult of 8 <= MB
        const int FULL = mfull << 1;
        int mb, nh;
        if (bid < FULL) {
            nh = (bid >> 3) & 1;
            mb = ((bid >> 4) << 3) + (bid & 7);
        } else {
            const int r = bid - FULL;
            const int rem = MB - mfull;
            nh = (r >= rem) ? 1 : 0;
            mb = mfull + r - nh * rem;
        }
        m0 = mb * 128;
        n0 = nh * 160;
    }

    // ---- staging setup: A (2 threads/row), B (2.5 16B-units/thread) ----
    const int arow = tid >> 1, ahalf = tid & 1;
    const int gr = min(m0 + arow, M - 1);
    const unsigned short* a0p = A0 + (size_t)gr * a0s + ahalf * 16;
    const unsigned short* a1p = nullptr;
    const unsigned short* m1p = nullptr;
    if (KT1 > 0) {
        a1p = amsg + (size_t)b2a[gr] * 320 + ahalf * 16;
        m1p = msg + (size_t)b2revb[gr] * 320 + ahalf * 16;
    }
    const int u0 = tid, u1 = tid + 256, u2 = tid + 512;
    const unsigned short* bg0 = Wt + (size_t)(n0 + (u0 >> 2)) * BSTRIDE + ((u0 ^ (u0 >> 2)) & 3) * 8;
    const unsigned short* bg1 = Wt + (size_t)(n0 + (u1 >> 2)) * BSTRIDE + ((u1 ^ (u1 >> 2)) & 3) * 8;
    const unsigned short* bg2 = (tid < 128)
        ? Wt + (size_t)(n0 + (u2 >> 2)) * BSTRIDE + ((u2 ^ (u2 >> 2)) & 3) * 8 : Wt;

    // ---- fragment LDS offsets (shorts) ----
    int aoff[4], boff[5];
#pragma unroll
    for (int tm = 0; tm < 4; ++tm)
        aoff[tm] = (wm * 64 + tm * 16 + l16) * 40 + quad * 8;
#pragma unroll
    for (int tn = 0; tn < 5; ++tn) {
        int nl = wn * 80 + tn * 16 + l16;
        boff[tn] = nl * 32 + ((quad ^ nl) & 3) * 8;
    }

    floatx4 acc[4][5];
#pragma unroll
    for (int tm = 0; tm < 4; ++tm)
#pragma unroll
        for (int tn = 0; tn < 5; ++tn) acc[tm][tn] = (floatx4){0.f, 0.f, 0.f, 0.f};

    // ---- two named register prefetch sets (no arrays -> no scratch risk) ----
    uint4 pa0, pa1, pb0, pb1, pb2;   // set P: even kt
    uint4 qa0, qa1, qb0, qb1, qb2;   // set Q: odd kt

    auto ldg = [&](int kt, uint4& x0, uint4& x1, uint4& y0, uint4& y1, uint4& y2) {
        if (kt < KT0) {
            x0 = *(const uint4*)(a0p + kt * 32);
            x1 = *(const uint4*)(a0p + kt * 32 + 8);
        } else {
            int ko = (kt - KT0) * 32;
            uint4 va0 = *(const uint4*)(a1p + ko);
            uint4 va1 = *(const uint4*)(a1p + ko + 8);
            uint4 vm0 = *(const uint4*)(m1p + ko);
            uint4 vm1 = *(const uint4*)(m1p + ko + 8);
            x0 = bfsub8(va0, vm0);
            x1 = bfsub8(va1, vm1);
        }
        y0 = *(const uint4*)(bg0 + kt * 32);
        y1 = *(const uint4*)(bg1 + kt * 32);
        if (tid < 128) y2 = *(const uint4*)(bg2 + kt * 32);
    };
    auto stw = [&](int buf, const uint4& x0, const uint4& x1,
                   const uint4& y0, const uint4& y1, const uint4& y2) {
        unsigned short* ab = As + buf * 5120 + arow * 40 + ahalf * 16;
        *(uint4*)(ab) = x0;
        *(uint4*)(ab + 8) = x1;
        unsigned short* bb = Bs + buf * 5120;
        *(uint4*)(bb + u0 * 8) = y0;
        *(uint4*)(bb + u1 * 8) = y1;
        if (tid < 128) *(uint4*)(bb + u2 * 8) = y2;
    };
    // raw barrier: lgkmcnt(0) only (ds ordering); vmem ordering is handled by
    // the compiler's counted, dependence-driven vmcnt before the LDS stores.
    auto barsync = [&]() {
        asm volatile("s_waitcnt lgkmcnt(0)" ::: "memory");
        __builtin_amdgcn_sched_barrier(0);
        __builtin_amdgcn_s_barrier();
        __builtin_amdgcn_sched_barrier(0);
    };
    auto compute = [&](int buf) {
        bf16x8 av[4], bv[5];
#pragma unroll
        for (int tm = 0; tm < 4; ++tm)
            av[tm] = *(const bf16x8*)(As + buf * 5120 + aoff[tm]);
#pragma unroll
        for (int tn = 0; tn < 5; ++tn)
            bv[tn] = *(const bf16x8*)(Bs + buf * 5120 + boff[tn]);
#pragma unroll
        for (int tn = 0; tn < 5; ++tn)
#pragma unroll
            for (int tm = 0; tm < 4; ++tm)
                acc[tm][tn] = __builtin_amdgcn_mfma_f32_16x16x32_bf16(av[tm], bv[tn], acc[tm][tn], 0, 0, 0);
    };

    // ---- prologue: kt0 -> P -> LDS[0]; kt1 -> Q (in flight) ----
    ldg(0, pa0, pa1, pb0, pb1, pb2);
    if (KT > 1) ldg(1, qa0, qa1, qb0, qb1, qb2);
    stw(0, pa0, pa1, pb0, pb1, pb2);
    barsync();

#pragma unroll
    for (int kt = 0; kt < KT; ++kt) {
        if ((kt & 1) == 0) {
            if (kt + 2 < KT) ldg(kt + 2, pa0, pa1, pb0, pb1, pb2);
            compute(0);
            if (kt + 1 < KT) { stw(1, qa0, qa1, qb0, qb1, qb2); barsync(); }
        } else {
            if (kt + 2 < KT) ldg(kt + 2, qa0, qa1, qb0, qb1, qb2);
            compute(1);
            if (kt + 1 < KT) { stw(0, pa0, pa1, pb0, pb1, pb2); barsync(); }
        }
    }

    // ---- epilogue ----
    float bias[5];
    if (MODE == 2) {
#pragma unroll
        for (int tn = 0; tn < 5; ++tn) {
            int col = n0 + wn * 80 + tn * 16 + l16;
            bias[tn] = (col < 300) ? bo[col] : 0.f;
        }
    }
#pragma unroll
    for (int tm = 0; tm < 4; ++tm) {
        const int r0 = m0 + wm * 64 + tm * 16 + quad * 4;
#pragma unroll
        for (int tn = 0; tn < 5; ++tn) {
            const int col = n0 + wn * 80 + tn * 16 + l16;
#pragma unroll
            for (int i = 0; i < 4; ++i) {
                int r = r0 + i;
                if (r >= M) continue;
                float c = acc[tm][tn][i];
                if (MODE == 2) {
                    if (col < 300) hid[(size_t)r * 300 + col] = fmaxf(c + bias[tn], 0.f);
                } else {
                    outp[(size_t)r * 320 + col] = f2bf(fmaxf(c, 0.f));
                }
            }
        }
    }
}

// ---------------------------------------------------------------------------
// Per-molecule mean. mol_ids sorted -> binary search row range.
// ---------------------------------------------------------------------------
__global__ __launch_bounds__(320) void mean_k(const float* __restrict__ hid,
                                              const int* __restrict__ mol_ids,
                                              float* __restrict__ out, int nA) {
    int mol = blockIdx.x;
    int lo, hi;
    {
        int l = 0, h = nA;
        while (l < h) { int m = (l + h) >> 1; if (mol_ids[m] < mol) l = m + 1; else h = m; }
        lo = l;
    }
    {
        int l = lo, h = nA;
        while (l < h) { int m = (l + h) >> 1; if (mol_ids[m] < mol + 1) l = m + 1; else h = m; }
        hi = l;
    }
    int col = threadIdx.x;
    if (col >= 300) return;
    float s = 0.f;
    for (int a = lo; a < hi; ++a) s += hid[(size_t)a * 300 + col];
    int cnt = hi - lo;
    out[(size_t)mol * 300 + col] = s / (float)(cnt > 0 ? cnt : 1);
}

// ---------------------------------------------------------------------------
extern "C" void kernel_launch(void* const* d_in, const int* in_sizes, int n_in,
                              void* d_out, int out_size, void* d_ws, size_t ws_size,
                              hipStream_t stream) {
    (void)in_sizes; (void)n_in;
    const float* f_atoms = (const float*)d_in[0];
    const float* f_bonds = (const float*)d_in[1];
    const float* W_i     = (const float*)d_in[2];
    const float* W_h     = (const float*)d_in[3];
    const float* W_o     = (const float*)d_in[4];
    const float* b_o     = (const float*)d_in[5];
    const int*   a2b     = (const int*)d_in[6];
    const int*   b2a     = (const int*)d_in[7];
    const int*   b2revb  = (const int*)d_in[8];
    const int*   mol_ids = (const int*)d_in[9];

    const size_t sz_wih  = 320ull * 480 * 2;
    const size_t sz_wto  = 320ull * 448 * 2;
    const size_t sz_fbp  = 200000ull * 160 * 2;
    const size_t sz_amsg = 100000ull * 320 * 2;
    const size_t sz_msg  = 200000ull * 320 * 2;
    const size_t need = sz_wih + sz_wto + sz_fbp + sz_amsg + 2 * sz_msg;

    if (ws_size < need) {
        dbg_fill<<<(out_size + 255) / 256, 256, 0, stream>>>(
            (float*)d_out, out_size, (float)(ws_size >> 20));
        return;
    }

    char* ws = (char*)d_ws;
    unsigned short* wih  = (unsigned short*)(ws);
    unsigned short* wto  = (unsigned short*)(ws + sz_wih);
    unsigned short* fbp  = (unsigned short*)(ws + sz_wih + sz_wto);
    unsigned short* amsg = (unsigned short*)(ws + sz_wih + sz_wto + sz_fbp);
    unsigned short* msgA = (unsigned short*)(ws + sz_wih + sz_wto + sz_fbp + sz_amsg);
    unsigned short* msgB = (unsigned short*)(ws + sz_wih + sz_wto + sz_fbp + sz_amsg + sz_msg);
    unsigned short* concat = msgA;                     // msgA dead after loop
    float*          hid    = (float*)msgB;             // msgB dead after final gather

    prep_wih<<<600, 256, 0, stream>>>(W_i, W_h, wih);
    prep_wto<<<560, 256, 0, stream>>>(W_o, wto);
    pad_bonds<<<15625, 256, 0, stream>>>(f_bonds, fbp);

    // msgA = relu(f_bonds @ W_i)   (grid = 2*MB, XCD-paired decode inside)
    gemm_k<5, 0, 0, 480><<<dim3(3126), 256, 0, stream>>>(
        fbp, 160, nullptr, nullptr, nullptr, nullptr, wih, msgA, nullptr, nullptr, 200000);

    unsigned short* cur = msgA;
    unsigned short* other = msgB;
    for (int d = 0; d < 3; ++d) {   // DEPTH-1
        gather_sum<40><<<15625, 256, 0, stream>>>(cur, a2b, amsg, 320, 100000);
        gemm_k<5, 10, 0, 480><<<dim3(3126), 256, 0, stream>>>(
            fbp, 160, amsg, cur, b2a, b2revb, wih, other, nullptr, nullptr, 200000);
        unsigned short* t = cur; cur = other; other = t;
    }

    // final gather into concat cols 0..303 (cur == msgB; concat == msgA)
    gather_sum<38><<<14844, 256, 0, stream>>>(cur, a2b, concat, 448, 100000);
    atoms_concat<<<7032, 256, 0, stream>>>(f_atoms, concat);
    // hid = relu(concat @ W_o + b_o)
    gemm_k<14, 0, 2, 448><<<dim3(1564), 256, 0, stream>>>(
        concat, 448, nullptr, nullptr, nullptr, nullptr, wto, nullptr, hid, b_o, 100000);
    mean_k<<<8192, 320, 0, stream>>>(hid, mol_ids, (float*)d_out, 100000);
}